// Round 14
// baseline (2027.257 us; speedup 1.0000x reference)
//
#include <hip/hip_runtime.h>
#include <hip/hip_bf16.h>
#include <stdint.h>

typedef float  f32x4  __attribute__((ext_vector_type(4)));
typedef __bf16 bf16x8 __attribute__((ext_vector_type(8)));
typedef unsigned short u16x8 __attribute__((ext_vector_type(8)));

__device__ __forceinline__ unsigned short f2bf_rne(float f) {
    uint32_t x = __float_as_uint(f);
    uint32_t r = x + 0x7FFFu + ((x >> 16) & 1u);
    return (unsigned short)(r >> 16);
}

__global__ __launch_bounds__(256) void cvt_f32_bf16(const float* __restrict__ src,
                                                    unsigned short* __restrict__ dst,
                                                    long n) {
    long i0 = ((long)blockIdx.x * blockDim.x + threadIdx.x) * 8;
    long stride = (long)gridDim.x * blockDim.x * 8;
    for (long j = i0; j + 8 <= n; j += stride) {
        float4 v0 = *(const float4*)(src + j);
        float4 v1 = *(const float4*)(src + j + 4);
        u16x8 o;
        o[0] = f2bf_rne(v0.x); o[1] = f2bf_rne(v0.y);
        o[2] = f2bf_rne(v0.z); o[3] = f2bf_rne(v0.w);
        o[4] = f2bf_rne(v1.x); o[5] = f2bf_rne(v1.y);
        o[6] = f2bf_rne(v1.z); o[7] = f2bf_rne(v1.w);
        *(u16x8*)(dst + j) = o;
    }
}

#define GLL(SRC, DST) __builtin_amdgcn_global_load_lds(                      \
    (const __attribute__((address_space(1))) void*)(SRC),                    \
    (__attribute__((address_space(3))) void*)(DST), 16, 0, 0)
#define BARRIER() asm volatile("s_barrier" ::: "memory")
#define WAITV(N) asm volatile("s_waitcnt vmcnt(" #N ")" ::: "memory")
#define WAITL(N) do { asm volatile("s_waitcnt lgkmcnt(" #N ")" ::: "memory"); \
                      __builtin_amdgcn_sched_barrier(0); } while (0)

// 256x256, BK=64, 8 waves, 128KB dbuf LDS, r2/r8's verified 0-conflict layout.
// PINNED phases (r8 discipline: barrier + counted WAITL + sched_barrier)
// + one-phase read-ahead at <=96 frag regs (r13-proven no-spill budget):
//   P4(t-1): [vmcnt(6)+bar] read af(t)+bq(t); WAITL(12) pin; Q11(t-1)
//   P1(t): read af2; stage B0(t+1); bar; WAITL(8)  [drains af+bq]; Q00(af,bq)
//   P2(t): read bq2; stage A0(t+2); bar; WAITL(4)  [drains af2];   Q10(af2,bq)
//   P3(t):                          bar; WAITL(0)  [drains bq2];   Q01(af,bq2)
//   P4(t): stage B1+A1(t+2); vm gate; bar; read t+1; WAITL(12);    Q11(af2,bq2)
// Every MFMA's operands drained one full phase after issue (DS latency hidden
// under the prior MFMA cluster). LDS hazards: every region's reads drain
// (WAITL) >=1 closing barrier before its re-stage (B-nh1 stage moved to P4
// for exactly this). vmcnt ledger: 14 outstanding @P4 gate; WAITV(6) drains
// precisely tile t+1's 8 GLLs. vmcnt(0) for t>=NT-2 (guards break the count).
__global__ __launch_bounds__(512, 2) void gemm256_ra(
    const unsigned short* __restrict__ A, const unsigned short* __restrict__ B,
    const float* __restrict__ bias, float* __restrict__ C,
    int M, int N, int K) {
    __shared__ __align__(16) char lds[131072];
    const int tid  = threadIdx.x;
    const int lane = tid & 63;
    const int wave = tid >> 6;
    const int wr  = wave >> 2;   // 0..1
    const int wc  = wave & 3;    // 0..3
    const int l15 = lane & 15;
    const int l4  = lane >> 4;

    // two-level XCD super-tile mapping (round-8 verified: FETCH -37%)
    const int nwg = gridDim.x;
    const int Nt  = N >> 8;
    const int Mt  = M >> 8;
    const int bid = blockIdx.x;
    int tm, tn;
    if ((Mt & 7) == 0 && (Nt & 3) == 0 && (nwg & 255) == 0) {
        const int nst = nwg >> 5;
        const int q2  = nst >> 3;
        const int xc  = bid & 7;
        const int oo  = bid >> 3;
        const int idx = oo & 31;
        const int h   = oo >> 5;
        const int st  = xc * q2 + h;
        const int Mst = Mt >> 3;
        const int stm = st % Mst;
        const int stn = st / Mst;
        tm = stm * 8 + (idx & 7);
        tn = stn * 4 + (idx >> 3);
    } else {
        int qq = nwg >> 3, rr = nwg & 7, xc = bid & 7, oo = bid >> 3;
        int wg = (xc < rr ? xc * (qq + 1) : rr * (qq + 1) + (xc - rr) * qq) + oo;
        tm = wg / Nt; tn = wg % Nt;
    }
    const long m0 = (long)tm << 8;
    const long n0 = (long)tn << 8;

    const int colSw = ((tid & 7) ^ ((tid >> 3) & 7)) << 3;
    const int aRow  = tid >> 3;
    const int bWcLo = tid >> 8;
    const int bR    = (tid >> 3) & 31;
    const long Kl = K;

    auto STAGE_A = [&](int buf, int u, int t) {
        char* dst = lds + (buf << 16) + (u << 14) + tid * 16;
        long col = (long)t * 64 + colSw;
#pragma unroll
        for (int i = 0; i < 2; ++i) {
            const unsigned short* src = A + (m0 + i * 128 + u * 64 + aRow) * Kl + col;
            GLL(src, dst + i * 8192);
        }
    };
    auto STAGE_B = [&](int buf, int u, int t) {
        char* dst = lds + (buf << 16) + 32768 + (u << 14) + tid * 16;
        long col = (long)t * 64 + colSw;
#pragma unroll
        for (int i = 0; i < 2; ++i) {
            const unsigned short* src = B + (n0 + (i * 2 + bWcLo) * 64 + u * 32 + bR) * Kl + col;
            GLL(src, dst + i * 8192);
        }
    };
    auto LDA = [&](int buf, int mh, int m, int kk) -> bf16x8 {
        int off = (((m * 16 + l15) * 64 + kk * 32 + l4 * 8) * 2) ^ ((l15 & 7) << 4);
        return *(const bf16x8*)(lds + (buf << 16) + (mh << 14) + (wr << 13) + off);
    };
    auto LDB = [&](int buf, int nh, int n, int kk) -> bf16x8 {
        int off = (((n * 16 + l15) * 64 + kk * 32 + l4 * 8) * 2) ^ ((l15 & 7) << 4);
        return *(const bf16x8*)(lds + (buf << 16) + 32768 + (nh << 14) + (wc << 12) + off);
    };

    f32x4 acc[8][4] = {};                 // 128 AGPR
    bf16x8 af[4][2], af2[4][2];           // fixed roles: mh0 / mh1
    bf16x8 bq[2][2], bq2[2][2];           // fixed roles: nh0 / nh1

    auto RD_A = [&](bf16x8 (&d)[4][2], int buf, int mh) {
#pragma unroll
        for (int m = 0; m < 4; ++m) { d[m][0] = LDA(buf, mh, m, 0); d[m][1] = LDA(buf, mh, m, 1); }
    };
    auto RD_B = [&](bf16x8 (&d)[2][2], int buf, int nh) {
#pragma unroll
        for (int n = 0; n < 2; ++n) { d[n][0] = LDB(buf, nh, n, 0); d[n][1] = LDB(buf, nh, n, 1); }
    };
    auto MFMA_Q = [&](bf16x8 (&a_)[4][2], bf16x8 (&b_)[2][2], int mo, int no) {
        __builtin_amdgcn_s_setprio(1);
#pragma unroll
        for (int kk = 0; kk < 2; ++kk)
#pragma unroll
            for (int m = 0; m < 4; ++m)
#pragma unroll
                for (int n = 0; n < 2; ++n)
                    acc[mo + m][no + n] = __builtin_amdgcn_mfma_f32_16x16x32_bf16(
                        a_[m][kk], b_[n][kk], acc[mo + m][no + n], 0, 0, 0);
        __builtin_amdgcn_s_setprio(0);
    };

    const int NT = K >> 6;

    // prologue: t0 complete, drain; seed steady in-flight pattern
    // {A0(t1), B1(t1), A1(t1)} (B0(t1) staged at P1(0)).
    STAGE_A(0, 0, 0); STAGE_B(0, 0, 0); STAGE_B(0, 1, 0); STAGE_A(0, 1, 0);
    WAITV(0);
    STAGE_A(1, 0, 1); STAGE_B(1, 1, 1); STAGE_A(1, 1, 1);
    BARRIER();                    // tile0 visible
    RD_A(af, 0, 0);               // af(t0, mh0)  [virtual P4(-1)]
    RD_B(bq, 0, 0);               // bq(t0, nh0)

    for (int t = 0; t < NT; ++t) {
        const int cur = t & 1, nxt = cur ^ 1;
        // ---- P1: read af2 ; stage B0(t+1) ; Q00(af,bq) ----
        RD_A(af2, cur, 1);
        if (t + 1 < NT) STAGE_B(nxt, 0, t + 1);
        BARRIER(); WAITL(8);      // drains af+bq (oldest 12 of 20)
        MFMA_Q(af, bq, 0, 0);
        BARRIER();
        // ---- P2: read bq2 ; stage A0(t+2) ; Q10(af2,bq) ----
        RD_B(bq2, cur, 1);
        if (t + 2 < NT) STAGE_A(cur, 0, t + 2);
        BARRIER(); WAITL(4);      // drains af2 (oldest 8 of 12)
        MFMA_Q(af2, bq, 4, 0);
        BARRIER();
        // ---- P3: Q01(af,bq2) ----
        BARRIER(); WAITL(0);      // drains bq2 (issued a full phase ago)
        MFMA_Q(af, bq2, 0, 2);
        BARRIER();
        // ---- P4: stage B1+A1(t+2) ; vis gate ; read t+1 ; Q11(af2,bq2) ----
        if (t + 2 < NT) { STAGE_B(cur, 1, t + 2); STAGE_A(cur, 1, t + 2); }
        if (t >= NT - 2) { WAITV(0); } else { WAITV(6); }
        BARRIER();                // tile t+1 visible
        if (t + 1 < NT) {
            RD_A(af, nxt, 0);
            RD_B(bq, nxt, 0);
            WAITL(12);            // no-op pin (keeps the 12 new reads in flight)
        } else {
            WAITL(0);
        }
        MFMA_Q(af2, bq2, 4, 2);
        BARRIER();
    }

    // epilogue: D mapping col = l15, row = l4*4 + j within each 16x16 fragment
#pragma unroll
    for (int nf = 0; nf < 4; ++nf) {
        const long col = n0 + wc * 64 + nf * 16 + l15;
        const float bv = bias[col];
#pragma unroll
        for (int mf = 0; mf < 8; ++mf) {
            float* Cp = C + (m0 + wr * 128 + mf * 16 + l4 * 4) * (long)N + col;
#pragma unroll
            for (int j = 0; j < 4; ++j)
                Cp[(long)j * N] = acc[mf][nf][j] + bv;
        }
    }
}

// fallback: m97-structure 128x128 (verified round 1)
__global__ __launch_bounds__(256) void gemm_bt_bias(const unsigned short* __restrict__ A,
                                                    const unsigned short* __restrict__ B,
                                                    const float* __restrict__ bias,
                                                    float* __restrict__ C,
                                                    int M, int N, int K) {
    __shared__ unsigned short lds_a[128 * 32];
    __shared__ unsigned short lds_b[128 * 32];
    const int tid  = threadIdx.x;
    const int lane = tid & 63;
    const int wave = tid >> 6;
    const int wrr = wave >> 1, wcc = wave & 1;
    const int l15 = lane & 15, l4 = lane >> 4;
    const int nTilesN = N / 128;
    const long m0 = (long)(blockIdx.x / nTilesN) * 128;
    const long n0 = (long)(blockIdx.x % nTilesN) * 128;
    f32x4 acc[4][4] = {};
    const unsigned short* aSrc = A + (m0 + (tid >> 2)) * (long)K + ((tid & 3) * 8);
    const unsigned short* bSrc = B + (n0 + (tid >> 2)) * (long)K + ((tid & 3) * 8);
    char* aDst = (char*)lds_a + tid * 16;
    char* bDst = (char*)lds_b + tid * 16;
    for (int k0 = 0; k0 < K; k0 += 32) {
#pragma unroll
        for (int i = 0; i < 2; i++) {
            GLL(aSrc + (long)i * 64 * K + k0, aDst + i * 4096);
            GLL(bSrc + (long)i * 64 * K + k0, bDst + i * 4096);
        }
        __syncthreads();
        bf16x8 afr[4], bfr[4];
#pragma unroll
        for (int r = 0; r < 4; r++)
            afr[r] = *(const bf16x8*)&lds_a[(wrr * 64 + r * 16 + l15) * 32 + l4 * 8];
#pragma unroll
        for (int c = 0; c < 4; c++)
            bfr[c] = *(const bf16x8*)&lds_b[(wcc * 64 + c * 16 + l15) * 32 + l4 * 8];
#pragma unroll
        for (int r = 0; r < 4; r++)
#pragma unroll
            for (int c = 0; c < 4; c++)
                acc[r][c] = __builtin_amdgcn_mfma_f32_16x16x32_bf16(afr[r], bfr[c], acc[r][c], 0, 0, 0);
        __syncthreads();
    }
#pragma unroll
    for (int c = 0; c < 4; c++) {
        const long n = n0 + wcc * 64 + c * 16 + l15;
        const float bv = bias[n];
#pragma unroll
        for (int r = 0; r < 4; r++) {
            const long m = m0 + wrr * 64 + r * 16 + l4 * 4;
            float* Cp = C + m * (long)N + n;
#pragma unroll
            for (int j = 0; j < 4; j++)
                Cp[(long)j * N] = acc[r][c][j] + bv;
        }
    }
}

extern "C" void kernel_launch(void* const* d_in, const int* in_sizes, int n_in,
                              void* d_out, int out_size, void* d_ws, size_t ws_size,
                              hipStream_t stream) {
    const float* x    = (const float*)d_in[0];
    const float* w    = (const float*)d_in[1];
    const float* bias = (const float*)d_in[2];
    float* out = (float*)d_out;

    const long Nn = in_sizes[2];             // OUT = 4096
    const long Kk = (long)in_sizes[1] / Nn;  // IN  = 16384
    const long Mm = (long)in_sizes[0] / Kk;  // B*S = 8192

    unsigned short* aB = (unsigned short*)d_ws;
    unsigned short* bB = aB + Mm * Kk;
    cvt_f32_bf16<<<2048, 256, 0, stream>>>(x, aB, Mm * Kk);
    cvt_f32_bf16<<<2048, 256, 0, stream>>>(w, bB, Nn * Kk);

    if ((Mm & 255) == 0 && (Nn & 255) == 0 && (Kk & 127) == 0 && Kk >= 256) {
        const int grid = (int)((Mm >> 8) * (Nn >> 8));
        gemm256_ra<<<grid, 512, 0, stream>>>(aB, bB, bias, out, (int)Mm, (int)Nn, (int)Kk);
    } else {
        const int grid = (int)((Mm / 128) * (Nn / 128));
        gemm_bt_bias<<<grid, 256, 0, stream>>>(aB, bB, bias, out, (int)Mm, (int)Nn, (int)Kk);
    }
}

// Round 15
// 1098.407 us; speedup vs baseline: 1.8456x; 1.8456x over previous
//
#include <hip/hip_runtime.h>
#include <hip/hip_bf16.h>
#include <stdint.h>

typedef float  f32x4  __attribute__((ext_vector_type(4)));
typedef __bf16 bf16x8 __attribute__((ext_vector_type(8)));
typedef unsigned short u16x8 __attribute__((ext_vector_type(8)));

__device__ __forceinline__ unsigned short f2bf_rne(float f) {
    uint32_t x = __float_as_uint(f);
    uint32_t r = x + 0x7FFFu + ((x >> 16) & 1u);
    return (unsigned short)(r >> 16);
}

__global__ __launch_bounds__(256) void cvt_f32_bf16(const float* __restrict__ src,
                                                    unsigned short* __restrict__ dst,
                                                    long n) {
    long i0 = ((long)blockIdx.x * blockDim.x + threadIdx.x) * 8;
    long stride = (long)gridDim.x * blockDim.x * 8;
    for (long j = i0; j + 8 <= n; j += stride) {
        float4 v0 = *(const float4*)(src + j);
        float4 v1 = *(const float4*)(src + j + 4);
        u16x8 o;
        o[0] = f2bf_rne(v0.x); o[1] = f2bf_rne(v0.y);
        o[2] = f2bf_rne(v0.z); o[3] = f2bf_rne(v0.w);
        o[4] = f2bf_rne(v1.x); o[5] = f2bf_rne(v1.y);
        o[6] = f2bf_rne(v1.z); o[7] = f2bf_rne(v1.w);
        *(u16x8*)(dst + j) = o;
    }
}

#define GLL(SRC, DST) __builtin_amdgcn_global_load_lds(                      \
    (const __attribute__((address_space(1))) void*)(SRC),                    \
    (__attribute__((address_space(3))) void*)(DST), 16, 0, 0)
#define BARRIER() asm volatile("s_barrier" ::: "memory")
#define WAITV(N) asm volatile("s_waitcnt vmcnt(" #N ")" ::: "memory")
#define WAITL(N) do { asm volatile("s_waitcnt lgkmcnt(" #N ")" ::: "memory"); \
                      __builtin_amdgcn_sched_barrier(0); } while (0)

// 256x256, BK=64, 8 waves, 128KB dbuf LDS, r2/r8's verified 0-conflict layout.
// r8's discipline (in-phase reads -> barrier -> WAITL(0)+sched_barrier -> MFMA)
// with phases MERGED 4->2 per tile: 4 barriers/tile instead of 8 (theory:
// residual cost = barrier-skew repay events, ~150cyc x 16/tile at r8).
//  PhaseA: read af(u0,8)+bq(Bu0,4)+bq2(Bu1,4); stage A-u1(nxt,t+1)[deferred];
//          BAR; WAITL(0); Q00+Q01 (32 MFMA); BAR
//  PhaseB: read af2(u1,8); stage A-u0,B-u0,B-u1 (cur,t+2); WAITV(6); BAR;
//          WAITL(0); Q10+Q11 (32 MFMA); BAR
// Ledger: steady outstanding @gate = 14 = [t-1B:6][tA:2][tB:6]; WAITV(6)
// drains oldest 8 = exactly tile t+1's units. WAITV(0) for t>=NT-3 (guards).
// Hazards: every unit's stage is >=1 closing barrier after its reads' WAITL
// drain (A-u1's stage deferred to next PhaseA precisely for this).
// Frag regs 96 (af/af2/bq/bq2 fixed roles); bq/bq2 live across 1 barrier
// (r2-precedented, 112 VGPR no spill).
__global__ __launch_bounds__(512, 2) void gemm256_m2(
    const unsigned short* __restrict__ A, const unsigned short* __restrict__ B,
    const float* __restrict__ bias, float* __restrict__ C,
    int M, int N, int K) {
    __shared__ __align__(16) char lds[131072];
    const int tid  = threadIdx.x;
    const int lane = tid & 63;
    const int wave = tid >> 6;
    const int wr  = wave >> 2;   // 0..1
    const int wc  = wave & 3;    // 0..3
    const int l15 = lane & 15;
    const int l4  = lane >> 4;

    // two-level XCD super-tile mapping (round-8 verified: FETCH -37%)
    const int nwg = gridDim.x;
    const int Nt  = N >> 8;
    const int Mt  = M >> 8;
    const int bid = blockIdx.x;
    int tm, tn;
    if ((Mt & 7) == 0 && (Nt & 3) == 0 && (nwg & 255) == 0) {
        const int nst = nwg >> 5;
        const int q2  = nst >> 3;
        const int xc  = bid & 7;
        const int oo  = bid >> 3;
        const int idx = oo & 31;
        const int h   = oo >> 5;
        const int st  = xc * q2 + h;
        const int Mst = Mt >> 3;
        const int stm = st % Mst;
        const int stn = st / Mst;
        tm = stm * 8 + (idx & 7);
        tn = stn * 4 + (idx >> 3);
    } else {
        int qq = nwg >> 3, rr = nwg & 7, xc = bid & 7, oo = bid >> 3;
        int wg = (xc < rr ? xc * (qq + 1) : rr * (qq + 1) + (xc - rr) * qq) + oo;
        tm = wg / Nt; tn = wg % Nt;
    }
    const long m0 = (long)tm << 8;
    const long n0 = (long)tn << 8;

    const int colSw = ((tid & 7) ^ ((tid >> 3) & 7)) << 3;
    const int aRow  = tid >> 3;
    const int bWcLo = tid >> 8;
    const int bR    = (tid >> 3) & 31;
    const long Kl = K;

    auto STAGE_A = [&](int buf, int u, int t) {
        char* dst = lds + (buf << 16) + (u << 14) + tid * 16;
        long col = (long)t * 64 + colSw;
#pragma unroll
        for (int i = 0; i < 2; ++i) {
            const unsigned short* src = A + (m0 + i * 128 + u * 64 + aRow) * Kl + col;
            GLL(src, dst + i * 8192);
        }
    };
    auto STAGE_B = [&](int buf, int u, int t) {
        char* dst = lds + (buf << 16) + 32768 + (u << 14) + tid * 16;
        long col = (long)t * 64 + colSw;
#pragma unroll
        for (int i = 0; i < 2; ++i) {
            const unsigned short* src = B + (n0 + (i * 2 + bWcLo) * 64 + u * 32 + bR) * Kl + col;
            GLL(src, dst + i * 8192);
        }
    };
    auto LDA = [&](int buf, int mh, int m, int kk) -> bf16x8 {
        int off = (((m * 16 + l15) * 64 + kk * 32 + l4 * 8) * 2) ^ ((l15 & 7) << 4);
        return *(const bf16x8*)(lds + (buf << 16) + (mh << 14) + (wr << 13) + off);
    };
    auto LDB = [&](int buf, int nh, int n, int kk) -> bf16x8 {
        int off = (((n * 16 + l15) * 64 + kk * 32 + l4 * 8) * 2) ^ ((l15 & 7) << 4);
        return *(const bf16x8*)(lds + (buf << 16) + 32768 + (nh << 14) + (wc << 12) + off);
    };

    f32x4 acc[8][4] = {};                 // 128 AGPR
    bf16x8 af[4][2], af2[4][2];           // fixed roles: mh0 / mh1
    bf16x8 bq[2][2], bq2[2][2];           // fixed roles: nh0 / nh1

    auto RD_A = [&](bf16x8 (&d)[4][2], int buf, int mh) {
#pragma unroll
        for (int m = 0; m < 4; ++m) { d[m][0] = LDA(buf, mh, m, 0); d[m][1] = LDA(buf, mh, m, 1); }
    };
    auto RD_B = [&](bf16x8 (&d)[2][2], int buf, int nh) {
#pragma unroll
        for (int n = 0; n < 2; ++n) { d[n][0] = LDB(buf, nh, n, 0); d[n][1] = LDB(buf, nh, n, 1); }
    };
    auto MFMA_Q = [&](bf16x8 (&a_)[4][2], bf16x8 (&b_)[2][2], int mo, int no) {
        __builtin_amdgcn_s_setprio(1);
#pragma unroll
        for (int kk = 0; kk < 2; ++kk)
#pragma unroll
            for (int m = 0; m < 4; ++m)
#pragma unroll
                for (int n = 0; n < 2; ++n)
                    acc[mo + m][no + n] = __builtin_amdgcn_mfma_f32_16x16x32_bf16(
                        a_[m][kk], b_[n][kk], acc[mo + m][no + n], 0, 0, 0);
        __builtin_amdgcn_s_setprio(0);
    };

    const int NT = K >> 6;

    // prologue: t0 all 4 units (8 GLL); t1 {A-u0, B-u0, B-u1} (6 GLL);
    // WAITV(6) drains t0's 8, leaves t1's 6 in flight; barrier publishes t0.
    STAGE_A(0, 0, 0); STAGE_A(0, 1, 0); STAGE_B(0, 0, 0); STAGE_B(0, 1, 0);
    STAGE_A(1, 0, 1); STAGE_B(1, 0, 1); STAGE_B(1, 1, 1);
    WAITV(6);
    BARRIER();

    for (int t = 0; t < NT; ++t) {
        const int cur = t & 1, nxt = cur ^ 1;
        // ---- PhaseA: reads af,bq,bq2 ; deferred stage A-u1(nxt,t+1) ----
        RD_A(af, cur, 0);                 // 8 ds (A unit0)
        RD_B(bq, cur, 0);                 // 4 ds (B unit0)
        RD_B(bq2, cur, 1);                // 4 ds (B unit1)
        if (t + 1 < NT) STAGE_A(nxt, 1, t + 1);   // 2 GLL
        BARRIER(); WAITL(0);
        MFMA_Q(af, bq, 0, 0);             // Q00
        MFMA_Q(af, bq2, 0, 2);            // Q01
        BARRIER();
        // ---- PhaseB: read af2 ; stage 3 units (cur,t+2) ; gate ; MFMA ----
        RD_A(af2, cur, 1);                // 8 ds (A unit1)
        if (t + 2 < NT) {
            STAGE_A(cur, 0, t + 2);
            STAGE_B(cur, 0, t + 2);
            STAGE_B(cur, 1, t + 2);       // 6 GLL
        }
        if (t >= NT - 3) { WAITV(0); } else { WAITV(6); }
        BARRIER(); WAITL(0);
        MFMA_Q(af2, bq, 4, 0);            // Q10
        MFMA_Q(af2, bq2, 4, 2);           // Q11
        BARRIER();
    }

    // epilogue: D mapping col = l15, row = l4*4 + j within each 16x16 fragment
#pragma unroll
    for (int nf = 0; nf < 4; ++nf) {
        const long col = n0 + wc * 64 + nf * 16 + l15;
        const float bv = bias[col];
#pragma unroll
        for (int mf = 0; mf < 8; ++mf) {
            float* Cp = C + (m0 + wr * 128 + mf * 16 + l4 * 4) * (long)N + col;
#pragma unroll
            for (int j = 0; j < 4; ++j)
                Cp[(long)j * N] = acc[mf][nf][j] + bv;
        }
    }
}

// fallback: m97-structure 128x128 (verified round 1)
__global__ __launch_bounds__(256) void gemm_bt_bias(const unsigned short* __restrict__ A,
                                                    const unsigned short* __restrict__ B,
                                                    const float* __restrict__ bias,
                                                    float* __restrict__ C,
                                                    int M, int N, int K) {
    __shared__ unsigned short lds_a[128 * 32];
    __shared__ unsigned short lds_b[128 * 32];
    const int tid  = threadIdx.x;
    const int lane = tid & 63;
    const int wave = tid >> 6;
    const int wrr = wave >> 1, wcc = wave & 1;
    const int l15 = lane & 15, l4 = lane >> 4;
    const int nTilesN = N / 128;
    const long m0 = (long)(blockIdx.x / nTilesN) * 128;
    const long n0 = (long)(blockIdx.x % nTilesN) * 128;
    f32x4 acc[4][4] = {};
    const unsigned short* aSrc = A + (m0 + (tid >> 2)) * (long)K + ((tid & 3) * 8);
    const unsigned short* bSrc = B + (n0 + (tid >> 2)) * (long)K + ((tid & 3) * 8);
    char* aDst = (char*)lds_a + tid * 16;
    char* bDst = (char*)lds_b + tid * 16;
    for (int k0 = 0; k0 < K; k0 += 32) {
#pragma unroll
        for (int i = 0; i < 2; i++) {
            GLL(aSrc + (long)i * 64 * K + k0, aDst + i * 4096);
            GLL(bSrc + (long)i * 64 * K + k0, bDst + i * 4096);
        }
        __syncthreads();
        bf16x8 afr[4], bfr[4];
#pragma unroll
        for (int r = 0; r < 4; r++)
            afr[r] = *(const bf16x8*)&lds_a[(wrr * 64 + r * 16 + l15) * 32 + l4 * 8];
#pragma unroll
        for (int c = 0; c < 4; c++)
            bfr[c] = *(const bf16x8*)&lds_b[(wcc * 64 + c * 16 + l15) * 32 + l4 * 8];
#pragma unroll
        for (int r = 0; r < 4; r++)
#pragma unroll
            for (int c = 0; c < 4; c++)
                acc[r][c] = __builtin_amdgcn_mfma_f32_16x16x32_bf16(afr[r], bfr[c], acc[r][c], 0, 0, 0);
        __syncthreads();
    }
#pragma unroll
    for (int c = 0; c < 4; c++) {
        const long n = n0 + wcc * 64 + c * 16 + l15;
        const float bv = bias[n];
#pragma unroll
        for (int r = 0; r < 4; r++) {
            const long m = m0 + wrr * 64 + r * 16 + l4 * 4;
            float* Cp = C + m * (long)N + n;
#pragma unroll
            for (int j = 0; j < 4; j++)
                Cp[(long)j * N] = acc[r][c][j] + bv;
        }
    }
}

extern "C" void kernel_launch(void* const* d_in, const int* in_sizes, int n_in,
                              void* d_out, int out_size, void* d_ws, size_t ws_size,
                              hipStream_t stream) {
    const float* x    = (const float*)d_in[0];
    const float* w    = (const float*)d_in[1];
    const float* bias = (const float*)d_in[2];
    float* out = (float*)d_out;

    const long Nn = in_sizes[2];             // OUT = 4096
    const long Kk = (long)in_sizes[1] / Nn;  // IN  = 16384
    const long Mm = (long)in_sizes[0] / Kk;  // B*S = 8192

    unsigned short* aB = (unsigned short*)d_ws;
    unsigned short* bB = aB + Mm * Kk;
    cvt_f32_bf16<<<2048, 256, 0, stream>>>(x, aB, Mm * Kk);
    cvt_f32_bf16<<<2048, 256, 0, stream>>>(w, bB, Nn * Kk);

    if ((Mm & 255) == 0 && (Nn & 255) == 0 && (Kk & 127) == 0 && Kk >= 256) {
        const int grid = (int)((Mm >> 8) * (Nn >> 8));
        gemm256_m2<<<grid, 512, 0, stream>>>(aB, bB, bias, out, (int)Mm, (int)Nn, (int)Kk);
    } else {
        const int grid = (int)((Mm / 128) * (Nn / 128));
        gemm_bt_bias<<<grid, 256, 0, stream>>>(aB, bB, bias, out, (int)Mm, (int)Nn, (int)Kk);
    }
}